// Round 6
// baseline (682.761 us; speedup 1.0000x reference)
//
#include <hip/hip_runtime.h>

// Problem constants (fixed instance from setup_inputs)
#define NB 2
#define LD 4800      // h0*w0
#define SD 4800      // h1*w1
#define CD 256
#define H0 60
#define W0 80
#define H1 60
#define W1 80
#define MG 2
#define THRESH 0.2f
#define SIM_SCALE (1.0f / (256.0f * 0.1f))   // 1/(C*TEMP)
#define GT 38        // ceil(4800/128)
#define GTS 19       // ceil(4800/256)  (pass0 s-tiles)
#define CAP 8192     // candidate-list capacity (elements with conf > THRESH)

typedef float f32x4 __attribute__((ext_vector_type(4)));
typedef __bf16 bf16x8 __attribute__((ext_vector_type(8)));
typedef unsigned short u16x8 __attribute__((ext_vector_type(8)));

#define GLOBAL_AS __attribute__((address_space(1)))
#define LDS_AS __attribute__((address_space(3)))

__device__ __forceinline__ void gl_lds16(const unsigned short* g, unsigned short* l) {
    // async global->LDS, 16 B/lane; LDS dest = wave-uniform base + lane*16
    __builtin_amdgcn_global_load_lds((const GLOBAL_AS unsigned int*)g,
                                     (LDS_AS unsigned int*)l, 16, 0, 0);
}

__device__ __forceinline__ unsigned short f2bf(float f) {
    // round-to-nearest-even fp32 -> bf16 (inputs are finite normals)
    unsigned int u = __float_as_uint(f);
    u = u + 0x7FFFu + ((u >> 16) & 1u);
    return (unsigned short)(u >> 16);
}

__device__ __forceinline__ bool interior0(int idx) {
    int i = idx / W0, j = idx % W0;
    return (i >= MG) & (i < H0 - MG) & (j >= MG) & (j < W0 - MG);
}
__device__ __forceinline__ bool interior1(int idx) {
    int i = idx / W1, j = idx % W1;
    return (i >= MG) & (i < H1 - MG) & (j >= MG) & (j < W1 - MG);
}

// --------------------- K0: fused bf16 convert (f0+f1) + stats/counter zero
__global__ __launch_bounds__(256) void k_init(const float* __restrict__ f0,
                                              const float* __restrict__ f1,
                                              unsigned short* __restrict__ bf0,
                                              unsigned short* __restrict__ bf1,
                                              float* __restrict__ stats, int nstat) {
    const int per = NB * LD * CD / 8;            // 307200 8-elem chunks per feature
    int t = blockIdx.x * 256 + threadIdx.x;      // 0 .. 614399
    if (t < 2 * per) {
        const float* src;
        unsigned short* dst;
        int i;
        if (t < per) { src = f0; dst = bf0; i = t; }
        else         { src = f1; dst = bf1; i = t - per; }
        const float4* s = (const float4*)src + (size_t)i * 2;
        float4 a = s[0], b = s[1];
        u16x8 o = {f2bf(a.x), f2bf(a.y), f2bf(a.z), f2bf(a.w),
                   f2bf(b.x), f2bf(b.y), f2bf(b.z), f2bf(b.w)};
        *(u16x8*)(dst + (size_t)i * 8) = o;
    }
    if (t < nstat) stats[t] = 0.f;               // rowsum/colsum/rowmax/colmax/cnt
}

// ----------------------------------- K1: pass0 sums GEMM, 128x256 tile, 8 waves
// rowsum[n,l]=sum_s exp(sim), colsum[n,s]=sum_l exp(sim).
// Wave grid 2x4 (wm in {0,64}, wn in {0,64,128,192}); per-wave 64x64 tile and
// epilogue identical to the proven 128x128 kernel. 1444 blocks (vs 2888):
// halves barrier-drain events, cuts staged bytes 25%. Partial-sum segments
// are the same 64-wide groups as before -> identical numerics (atomic order
// aside, which was already non-deterministic).
__global__ __launch_bounds__(512) void k_sums(const unsigned short* __restrict__ bA,
                                              const unsigned short* __restrict__ bB,
                                              float* __restrict__ rowsum,
                                              float* __restrict__ colsum) {
    __shared__ __align__(16) unsigned short As[128][32];
    __shared__ __align__(16) unsigned short Bs[256][32];

    const int n  = blockIdx.z;
    const int s0 = blockIdx.x * 256;
    const int l0 = blockIdx.y * 128;
    const int tid  = threadIdx.x;
    const int lane = tid & 63;
    const int wave = tid >> 6;           // 0..7
    const int wm = (wave >> 2) * 64;     // row offset in tile
    const int wn = (wave & 3) * 64;      // col offset in tile
    const int quad = lane >> 4;
    const int lr   = lane & 15;

    // staging: 512 threads; A = 128 rows (1 instr/thread), B = 256 rows (2).
    // thread t -> row t/4, 16B chunk (t%4); wave w spans rows [w*16, w*16+16)
    // so LDS dest = wave-uniform base + lane*16 (gl_lds16 contract).
    const int srow = tid >> 2;
    const int schunk = (tid & 3) * 8;
    const unsigned short* ga  = bA + ((size_t)n * LD + min(l0 + srow,       LD - 1)) * CD + schunk;
    const unsigned short* gb0 = bB + ((size_t)n * SD + min(s0 + srow,       SD - 1)) * CD + schunk;
    const unsigned short* gb1 = bB + ((size_t)n * SD + min(s0 + srow + 128, SD - 1)) * CD + schunk;
    unsigned short* la  = &As[wave * 16][0];
    unsigned short* lb0 = &Bs[wave * 16][0];
    unsigned short* lb1 = &Bs[wave * 16 + 128][0];

    f32x4 acc[4][4];
#pragma unroll
    for (int i = 0; i < 4; ++i)
#pragma unroll
        for (int j = 0; j < 4; ++j) acc[i][j] = (f32x4){0.f, 0.f, 0.f, 0.f};

    for (int k0 = 0; k0 < CD; k0 += 32) {
        __syncthreads();   // previous tile fully consumed
        gl_lds16(ga  + k0, la);
        gl_lds16(gb0 + k0, lb0);
        gl_lds16(gb1 + k0, lb1);
        __syncthreads();   // compiler drains vmcnt before barrier

        bf16x8 af[4], bfr[4];
#pragma unroll
        for (int i = 0; i < 4; ++i) {
            af[i]  = __builtin_bit_cast(bf16x8, *(const u16x8*)&As[wm + i * 16 + lr][quad * 8]);
            bfr[i] = __builtin_bit_cast(bf16x8, *(const u16x8*)&Bs[wn + i * 16 + lr][quad * 8]);
        }
#pragma unroll
        for (int i = 0; i < 4; ++i)
#pragma unroll
            for (int j = 0; j < 4; ++j)
                acc[i][j] = __builtin_amdgcn_mfma_f32_16x16x32_bf16(af[i], bfr[j], acc[i][j], 0, 0, 0);
    }

    // epilogue: C/D layout col=lane&15, row=quad*4+reg (m89)
    const int rb = l0 + wm;
    const int cb = s0 + wn;

    float rpart[4][4];   // [mi][reg] partial row sums over this wave's 64 cols
    float cpart[4];      // [ni]     partial col sums over this wave's 64 rows
#pragma unroll
    for (int i = 0; i < 4; ++i) {
        cpart[i] = 0.f;
#pragma unroll
        for (int g = 0; g < 4; ++g) rpart[i][g] = 0.f;
    }
#pragma unroll
    for (int mi = 0; mi < 4; ++mi)
#pragma unroll
        for (int ni = 0; ni < 4; ++ni)
#pragma unroll
            for (int g = 0; g < 4; ++g) {
                int row = rb + mi * 16 + quad * 4 + g;
                int col = cb + ni * 16 + lr;
                float sv = acc[mi][ni][g] * SIM_SCALE;
                bool ok = (row < LD) & (col < SD);
                float ev = ok ? __expf(sv) : 0.f;
                rpart[mi][g] += ev;
                cpart[ni] += ev;
            }
#pragma unroll
    for (int mi = 0; mi < 4; ++mi)
#pragma unroll
        for (int g = 0; g < 4; ++g) {
            float v = rpart[mi][g];
            v += __shfl_xor(v, 1);
            v += __shfl_xor(v, 2);
            v += __shfl_xor(v, 4);
            v += __shfl_xor(v, 8);
            int row = rb + mi * 16 + quad * 4 + g;
            if (lr == 0 && row < LD) atomicAdd(&rowsum[n * LD + row], v);
        }
#pragma unroll
    for (int ni = 0; ni < 4; ++ni) {
        float v = cpart[ni];
        v += __shfl_xor(v, 16);
        v += __shfl_xor(v, 32);
        int col = cb + ni * 16 + lr;
        if (quad == 0 && col < SD) atomicAdd(&colsum[n * SD + col], v);
    }
}

// ----------------------------------- K2: pass1 conf GEMM (proven R5 structure)
// conf = exp(sim)^2/(rowsum*colsum); fused zero-fill of mask+matched tiles;
// elements > THRESH (rare) feed predicated atomicMax row/col maxes + append
// list. 128x128 tile, 4 waves (2x2), wave tile 64x64. Write-BW-bound; do not
// restructure (R4 lesson).
__global__ __launch_bounds__(256) void k_conf(const unsigned short* __restrict__ bA,
                                              const unsigned short* __restrict__ bB,
                                              const float* __restrict__ rowsum,
                                              const float* __restrict__ colsum,
                                              float* __restrict__ conf,
                                              float* __restrict__ mask,   // matched = mask + NB*LD*SD
                                              unsigned int* __restrict__ rowmax,
                                              unsigned int* __restrict__ colmax,
                                              unsigned int* __restrict__ cnt,
                                              uint4* __restrict__ list) {
    __shared__ __align__(16) unsigned short As[128][32];
    __shared__ __align__(16) unsigned short Bs[128][32];

    const int n  = blockIdx.z;
    const int s0 = blockIdx.x * 128;
    const int l0 = blockIdx.y * 128;
    const int tid  = threadIdx.x;
    const int lane = tid & 63;
    const int wave = tid >> 6;
    const int wm = (wave >> 1) * 64;
    const int wn = (wave & 1) * 64;
    const int quad = lane >> 4;
    const int lr   = lane & 15;

    const int sr = wave * 32 + (lane >> 2);
    const int sc = (lane & 3) * 8;
    const unsigned short* ga0 = bA + ((size_t)n * LD + min(l0 + sr,      LD - 1)) * CD + sc;
    const unsigned short* ga1 = bA + ((size_t)n * LD + min(l0 + sr + 16, LD - 1)) * CD + sc;
    const unsigned short* gb0 = bB + ((size_t)n * SD + min(s0 + sr,      SD - 1)) * CD + sc;
    const unsigned short* gb1 = bB + ((size_t)n * SD + min(s0 + sr + 16, SD - 1)) * CD + sc;
    unsigned short* la0 = &As[wave * 32][0];
    unsigned short* la1 = &As[wave * 32 + 16][0];
    unsigned short* lb0 = &Bs[wave * 32][0];
    unsigned short* lb1 = &Bs[wave * 32 + 16][0];

    f32x4 acc[4][4];
#pragma unroll
    for (int i = 0; i < 4; ++i)
#pragma unroll
        for (int j = 0; j < 4; ++j) acc[i][j] = (f32x4){0.f, 0.f, 0.f, 0.f};

    for (int k0 = 0; k0 < CD; k0 += 32) {
        __syncthreads();
        gl_lds16(ga0 + k0, la0);
        gl_lds16(ga1 + k0, la1);
        gl_lds16(gb0 + k0, lb0);
        gl_lds16(gb1 + k0, lb1);
        __syncthreads();

        bf16x8 af[4], bfr[4];
#pragma unroll
        for (int i = 0; i < 4; ++i) {
            af[i]  = __builtin_bit_cast(bf16x8, *(const u16x8*)&As[wm + i * 16 + lr][quad * 8]);
            bfr[i] = __builtin_bit_cast(bf16x8, *(const u16x8*)&Bs[wn + i * 16 + lr][quad * 8]);
        }
#pragma unroll
        for (int i = 0; i < 4; ++i)
#pragma unroll
            for (int j = 0; j < 4; ++j)
                acc[i][j] = __builtin_amdgcn_mfma_f32_16x16x32_bf16(af[i], bfr[j], acc[i][j], 0, 0, 0);
    }

    const int rb = l0 + wm;
    const int cb = s0 + wn;

    // ---- fused zero-fill of this block's 128x128 tile in mask & matched
    {
        const size_t plane = (size_t)NB * LD * SD;
        f32x4* mask4  = (f32x4*)mask;
        f32x4* match4 = (f32x4*)(mask + plane);
        const int r0 = tid >> 5;          // 0..7
        const int c4 = tid & 31;          // float4 column index within tile
        const f32x4 z = {0.f, 0.f, 0.f, 0.f};
        if (s0 + c4 * 4 < SD) {           // 4800%4==0: no straddle
#pragma unroll
            for (int rr = 0; rr < 16; ++rr) {
                int row = l0 + r0 + rr * 8;
                if (row < LD) {
                    size_t o = ((size_t)n * LD + row) * (SD / 4) + (s0 / 4) + c4;
                    mask4[o]  = z;
                    match4[o] = z;
                }
            }
        }
    }

    float rinv[4][4], cinv[4];
#pragma unroll
    for (int mi = 0; mi < 4; ++mi)
#pragma unroll
        for (int g = 0; g < 4; ++g) {
            int row = min(rb + mi * 16 + quad * 4 + g, LD - 1);
            rinv[mi][g] = 1.0f / rowsum[n * LD + row];
        }
#pragma unroll
    for (int ni = 0; ni < 4; ++ni) {
        int col = min(cb + ni * 16 + lr, SD - 1);
        cinv[ni] = 1.0f / colsum[n * SD + col];
    }
#pragma unroll
    for (int mi = 0; mi < 4; ++mi)
#pragma unroll
        for (int ni = 0; ni < 4; ++ni)
#pragma unroll
            for (int g = 0; g < 4; ++g) {
                int row = rb + mi * 16 + quad * 4 + g;
                int col = cb + ni * 16 + lr;
                float sv = acc[mi][ni][g] * SIM_SCALE;
                float e = __expf(sv);
                float cv = e * e * rinv[mi][g] * cinv[ni];
                bool ok = (row < LD) & (col < SD);
                if (ok) {
                    conf[((size_t)n * LD + row) * SD + col] = cv;
                    if (cv > THRESH) {   // rare: predicated maxes + append
                        atomicMax(&rowmax[n * LD + row], __float_as_uint(cv));
                        atomicMax(&colmax[n * SD + col], __float_as_uint(cv));
                        unsigned int id = atomicAdd(cnt, 1u);
                        if (id < CAP) {
                            uint4 rec = {(unsigned)n, (unsigned)row, (unsigned)col,
                                         __float_as_uint(cv)};
                            list[id] = rec;
                        }
                    }
                }
            }
}

// ------------------------- K3: fixup the (rare) candidates into mask/matched
__global__ __launch_bounds__(256) void k_fix(const unsigned int* __restrict__ cnt,
                                             const uint4* __restrict__ list,
                                             const unsigned int* __restrict__ rowmax,
                                             const unsigned int* __restrict__ colmax,
                                             float* __restrict__ mask,
                                             float* __restrict__ matched) {
    unsigned int m = min(*cnt, (unsigned int)CAP);
    for (unsigned int i = threadIdx.x; i < m; i += 256) {
        uint4 r = list[i];
        int n = (int)r.x, row = (int)r.y, col = (int)r.z;
        unsigned int cb = r.w;   // bit pattern of cv (same bits as stored conf)
        if (cb == rowmax[n * LD + row] && cb == colmax[n * SD + col] &&
            interior0(row) && interior1(col)) {
            size_t o = ((size_t)n * LD + row) * SD + col;
            mask[o] = 1.f;
            matched[o] = __uint_as_float(cb);
        }
    }
}

extern "C" void kernel_launch(void* const* d_in, const int* in_sizes, int n_in,
                              void* d_out, int out_size, void* d_ws, size_t ws_size,
                              hipStream_t stream) {
    const float* f0 = (const float*)d_in[0];
    const float* f1 = (const float*)d_in[1];
    const size_t plane = (size_t)NB * LD * SD;
    float* conf = (float*)d_out;
    float* mask = conf + plane;      // mask + matched are contiguous (2*plane)

    // ws layout:
    // [rowsum NB*LD][colsum NB*SD][rowmaxu NB*LD][colmaxu NB*SD][cnt 4xu32]
    // [list CAP*uint4][bf0][bf1]
    float* rowsum = (float*)d_ws;
    float* colsum = rowsum + NB * LD;
    unsigned int* rowmaxu = (unsigned int*)(colsum + NB * SD);
    unsigned int* colmaxu = rowmaxu + NB * LD;
    unsigned int* cnt = colmaxu + NB * SD;               // 4 uints (1 used)
    uint4* list = (uint4*)(cnt + 4);
    unsigned short* bf0 = (unsigned short*)(list + CAP);
    unsigned short* bf1 = bf0 + (size_t)NB * LD * CD;

    // fused convert + stats zero: 2*307200 chunks, 38404 stats floats
    const int nstat = NB * (LD + SD) * 2 + 4;
    k_init<<<dim3(2 * NB * LD * CD / 8 / 256), 256, 0, stream>>>(f0, f1, bf0, bf1,
                                                                 rowsum, nstat);

    // pass 0: row/col exp-sums — 128x256 tile, 8 waves, 1444 blocks
    k_sums<<<dim3(GTS, GT, NB), 512, 0, stream>>>(bf0, bf1, rowsum, colsum);
    // pass 1: conf + fused mask/matched zero-fill + sparse candidate scan
    k_conf<<<dim3(GT, GT, NB), 256, 0, stream>>>(bf0, bf1, rowsum, colsum, conf, mask,
                                                 rowmaxu, colmaxu, cnt, list);
    k_fix<<<dim3(1), 256, 0, stream>>>(cnt, list, rowmaxu, colmaxu, mask, mask + plane);
}